// Round 9
// baseline (561.846 us; speedup 1.0000x reference)
//
#include <hip/hip_runtime.h>
#include <math.h>

#define B_TOK 8192
#define D_IN 1024
#define D_OUT 1024
#define N_E 8
#define N_H 128
#define SEL 2048

using bf16x8 = __attribute__((ext_vector_type(8))) short;
using floatx4 = __attribute__((ext_vector_type(4))) float;

__device__ __forceinline__ unsigned short f2bf(float f) {
  unsigned u = __float_as_uint(f);
  u = (u + 0x7FFFu + ((u >> 16) & 1u)) >> 16;
  return (unsigned short)u;
}

__device__ __forceinline__ float bf2f(unsigned short h) {
  return __uint_as_float(((unsigned)h) << 16);
}

__device__ __forceinline__ void async_cp16(const void* g, void* l) {
  __builtin_amdgcn_global_load_lds((__attribute__((address_space(1))) void*)g,
                                   (__attribute__((address_space(3))) void*)l,
                                   16, 0, 0);
}

// ---------------- router: 32 tokens/block, 4 tok x 4 col per thread ----------
// R6 structure (best measured): xs + w1/wg LDS-staged, simple __syncthreads,
// h in-reg -> fp64 logits, xb = bf16(x) emitted, w2 read from L2 in epilogue.
__global__ __launch_bounds__(256) void k_router(const float* __restrict__ x,
                                                const float* __restrict__ w1,
                                                const float* __restrict__ b1,
                                                const float* __restrict__ wg,
                                                const float* __restrict__ bg,
                                                const float* __restrict__ w2,
                                                const float* __restrict__ b2,
                                                unsigned short* __restrict__ xb,
                                                double* __restrict__ logits) {
  __shared__ __align__(16) char smem[37376];
  const int t = threadIdx.x;

  float (*xs)[36]   = (float(*)[36])(smem);              // 32x36x4  = 4608
  float (*ws1)[128] = (float(*)[128])(smem + 4608);      // 32x128x4 = 16384
  float (*wsg)[128] = (float(*)[128])(smem + 4608 + 16384);  // 16384
  const int b0 = blockIdx.x * 32;
  const int tg = t >> 5;   // 0..7 -> 4 tokens each
  const int og = t & 31;   // 0..31 -> 4 h-cols each
  const int xr = t >> 3, xc = (t & 7) * 4;   // xs loader coords

  double d1[4][4] = {}; double dg[4][4] = {};
  for (int k0 = 0; k0 < D_IN; k0 += 32) {
    __syncthreads();
    {
      float4 v = *(const float4*)(x + (size_t)(b0 + xr) * D_IN + k0 + xc);
      *(float4*)(&xs[xr][xc]) = v;
      ushort4 u; u.x = f2bf(v.x); u.y = f2bf(v.y); u.z = f2bf(v.z); u.w = f2bf(v.w);
      *(ushort4*)(xb + (size_t)(b0 + xr) * D_IN + k0 + xc) = u;
    }
    {
      int r = t >> 5, c = (t & 31) * 4;
#pragma unroll
      for (int p = 0; p < 4; ++p) {
        *(float4*)(&ws1[r + 8 * p][c]) = *(const float4*)(w1 + (size_t)(k0 + r + 8 * p) * N_H + c);
        *(float4*)(&wsg[r + 8 * p][c]) = *(const float4*)(wg + (size_t)(k0 + r + 8 * p) * N_H + c);
      }
    }
    __syncthreads();
    float a1[4][4] = {}; float ag[4][4] = {};
    for (int k = 0; k < 32; k += 4) {
      float xk[4][4];
#pragma unroll
      for (int i = 0; i < 4; ++i) {
        float4 xv = *(const float4*)(&xs[tg * 4 + i][k]);
        xk[i][0] = xv.x; xk[i][1] = xv.y; xk[i][2] = xv.z; xk[i][3] = xv.w;
      }
#pragma unroll
      for (int kk = 0; kk < 4; ++kk) {
        float4 w1v = *(const float4*)(&ws1[k + kk][og * 4]);
        float4 wgv = *(const float4*)(&wsg[k + kk][og * 4]);
        float wa1[4] = {w1v.x, w1v.y, w1v.z, w1v.w};
        float wag[4] = {wgv.x, wgv.y, wgv.z, wgv.w};
#pragma unroll
        for (int i = 0; i < 4; ++i) {
#pragma unroll
          for (int j = 0; j < 4; ++j) {
            a1[i][j] += xk[i][kk] * wa1[j];
            ag[i][j] += xk[i][kk] * wag[j];
          }
        }
      }
    }
#pragma unroll
    for (int i = 0; i < 4; ++i)
#pragma unroll
      for (int j = 0; j < 4; ++j) { d1[i][j] += a1[i][j]; dg[i][j] += ag[i][j]; }
  }

  float4 b1v = *(const float4*)(b1 + og * 4);
  float4 bgv = *(const float4*)(bg + og * 4);
  float b1a[4] = {b1v.x, b1v.y, b1v.z, b1v.w};
  float bga[4] = {bgv.x, bgv.y, bgv.z, bgv.w};
  float hv[4][4];
#pragma unroll
  for (int i = 0; i < 4; ++i) {
#pragma unroll
    for (int j = 0; j < 4; ++j) {
      float a = (float)d1[i][j] + b1a[j];
      float g = (float)dg[i][j] + bga[j];
      g = fmaxf(g, 0.f);
      hv[i][j] = fmaxf(a * g, 0.f);
    }
  }

  // logits partials (double); w2 read straight from L2 (4 KB, broadcast)
  double lp[4][8] = {};
#pragma unroll
  for (int j = 0; j < 4; ++j) {
    int kk = og * 4 + j;
    float4 wlo = *(const float4*)(w2 + kk * N_E);
    float4 whi = *(const float4*)(w2 + kk * N_E + 4);
    float w2a[8] = {wlo.x, wlo.y, wlo.z, wlo.w, whi.x, whi.y, whi.z, whi.w};
#pragma unroll
    for (int i = 0; i < 4; ++i) {
      double hj = (double)hv[i][j];
#pragma unroll
      for (int e = 0; e < 8; ++e)
        lp[i][e] += hj * (double)w2a[e];
    }
  }
#pragma unroll
  for (int o = 16; o; o >>= 1) {
#pragma unroll
    for (int i = 0; i < 4; ++i)
#pragma unroll
      for (int e = 0; e < 8; ++e)
        lp[i][e] += __shfl_down(lp[i][e], o);
  }
  if (og == 0) {
#pragma unroll
    for (int i = 0; i < 4; ++i)
#pragma unroll
      for (int e = 0; e < 8; ++e)
        logits[(size_t)(b0 + tg * 4 + i) * N_E + e] = lp[i][e] + (double)b2[e];
  }
}

// ---------------- fat kernel: topk (blocks 0..7) + weT cast (8..2055) --------
__global__ __launch_bounds__(256) void k_topk_fat(const double* __restrict__ logits,
                                                  const float* __restrict__ we,
                                                  int* __restrict__ ib, float* __restrict__ nws,
                                                  int* __restrict__ slot,
                                                  unsigned short* __restrict__ web) {
  __shared__ __align__(16) char smem[17408];
  const int t = threadIdx.x;

  if (blockIdx.x >= 8) {
    // ---- weT transpose+cast path ----
    const int wb = blockIdx.x - 8;            // 0..2047
    const int e = wb >> 8;                    // 8 experts x 256 tiles
    const int rem = wb & 255;
    const int o0 = (rem >> 4) * 64;
    const int d0 = (rem & 15) * 64;
    float (*tile)[68] = (float(*)[68])smem;   // 64x68x4 = 17408
    const float* wsrc = we + (size_t)e * D_IN * D_OUT;
    unsigned short* wdst = web + (size_t)e * D_OUT * D_IN;
    const int r = t >> 4;          // 0..15
    const int c = (t & 15) * 4;    // 0..60
#pragma unroll
    for (int p = 0; p < 4; ++p) {
      float4 v = *(const float4*)(wsrc + (size_t)(d0 + r + 16 * p) * D_OUT + o0 + c);
      tile[r + 16 * p][c] = v.x; tile[r + 16 * p][c + 1] = v.y;
      tile[r + 16 * p][c + 2] = v.z; tile[r + 16 * p][c + 3] = v.w;
    }
    __syncthreads();
#pragma unroll
    for (int p = 0; p < 4; ++p) {
      int orow = r + 16 * p;
      ushort4 v;
      v.x = f2bf(tile[c + 0][orow]); v.y = f2bf(tile[c + 1][orow]);
      v.z = f2bf(tile[c + 2][orow]); v.w = f2bf(tile[c + 3][orow]);
      *(ushort4*)(wdst + (size_t)(o0 + orow) * D_IN + d0 + c) = v;
    }
    return;
  }

  // ---- topk path (softmax axis=0 + exact top-2048 per expert) ----
  const int e = blockIdx.x;
  double* redd = (double*)smem;               // 4 doubles
  int* redi = (int*)(smem + 32);              // 4 ints
  unsigned* redu = (unsigned*)(smem + 48);    // 4 uints
  int* s_cnt = (int*)(smem + 64);

  double lv[32];
#pragma unroll
  for (int i = 0; i < 32; ++i) lv[i] = logits[(size_t)(t + i * 256) * N_E + e];

  double m = -1e300;
#pragma unroll
  for (int i = 0; i < 32; ++i) m = fmax(m, lv[i]);
  for (int o = 32; o; o >>= 1) m = fmax(m, __shfl_down(m, o));
  __syncthreads();
  if ((t & 63) == 0) redd[t >> 6] = m;
  __syncthreads();
  const double maxl = fmax(fmax(redd[0], redd[1]), fmax(redd[2], redd[3]));

  // cache exp(lv - maxl): reused for sum and keys (identical bits, half the exps)
  double ev[32];
#pragma unroll
  for (int i = 0; i < 32; ++i) ev[i] = exp(lv[i] - maxl);

  double s = 0.0;
#pragma unroll
  for (int i = 0; i < 32; ++i) s += ev[i];
  for (int o = 32; o; o >>= 1) s += __shfl_down(s, o);
  __syncthreads();
  if ((t & 63) == 0) redd[t >> 6] = s;
  __syncthreads();
  const double sum = redd[0] + redd[1] + redd[2] + redd[3];

  unsigned kr[32];
#pragma unroll
  for (int i = 0; i < 32; ++i) {
    float lf = (float)(ev[i] / sum);
    kr[i] = __float_as_uint(lf);
  }

  // ---- common-prefix skip: block min/max of keys ----
  unsigned mnk = 0xFFFFFFFFu, mxk = 0;
#pragma unroll
  for (int i = 0; i < 32; ++i) { mnk = (kr[i] < mnk) ? kr[i] : mnk; mxk = (kr[i] > mxk) ? kr[i] : mxk; }
  for (int o = 32; o; o >>= 1) {
    unsigned v = __shfl_down(mnk, o); mnk = (v < mnk) ? v : mnk;
    unsigned w = __shfl_down(mxk, o); mxk = (w > mxk) ? w : mxk;
  }
  __syncthreads();
  if ((t & 63) == 0) redu[t >> 6] = mnk;
  __syncthreads();
  mnk = redu[0]; if (redu[1] < mnk) mnk = redu[1]; if (redu[2] < mnk) mnk = redu[2]; if (redu[3] < mnk) mnk = redu[3];
  __syncthreads();
  if ((t & 63) == 0) redu[t >> 6] = mxk;
  __syncthreads();
  mxk = redu[0]; if (redu[1] > mxk) mxk = redu[1]; if (redu[2] > mxk) mxk = redu[2]; if (redu[3] > mxk) mxk = redu[3];

  const unsigned diff = mnk ^ mxk;
  int hb = -1;
  unsigned thr;
  if (diff == 0) {
    thr = mnk;
  } else {
    hb = 31 - __clz(diff);
    thr = mxk & ~((hb >= 31) ? 0xFFFFFFFFu : ((1u << (hb + 1)) - 1u));
  }

  for (int bit = hb; bit >= 0; --bit) {
    unsigned trial = thr | (1u << bit);
    int c = 0;
#pragma unroll
    for (int i = 0; i < 32; ++i) c += (kr[i] >= trial) ? 1 : 0;
    for (int o = 32; o; o >>= 1) c += __shfl_down(c, o);
    __syncthreads();
    if ((t & 63) == 0) redi[t >> 6] = c;
    __syncthreads();
    c = redi[0] + redi[1] + redi[2] + redi[3];
    if (c >= SEL) thr = trial;
  }

  int c1 = 0, ceq = 0;
#pragma unroll
  for (int i = 0; i < 32; ++i) {
    c1 += (kr[i] > thr) ? 1 : 0;
    ceq += (kr[i] == thr) ? 1 : 0;
  }
  for (int o = 32; o; o >>= 1) { c1 += __shfl_down(c1, o); ceq += __shfl_down(ceq, o); }
  __syncthreads();
  if ((t & 63) == 0) { redi[t >> 6] = c1; ((int*)redu)[t >> 6] = ceq; }
  __syncthreads();
  c1 = redi[0] + redi[1] + redi[2] + redi[3];
  ceq = ((int*)redu)[0] + ((int*)redu)[1] + ((int*)redu)[2] + ((int*)redu)[3];
  const int need = SEL - c1;

  int cut;
  if (ceq == need) {
    cut = B_TOK;
  } else {
    cut = 0;
    for (int bit = 12; bit >= 0; --bit) {
      int trial = cut | (1 << bit);
      int c = 0;
#pragma unroll
      for (int i = 0; i < 32; ++i) c += (kr[i] == thr && (t + i * 256) < trial) ? 1 : 0;
      for (int o = 32; o; o >>= 1) c += __shfl_down(c, o);
      __syncthreads();
      if ((t & 63) == 0) redi[t >> 6] = c;
      __syncthreads();
      c = redi[0] + redi[1] + redi[2] + redi[3];
      if (c < need) cut = trial;
    }
  }

  const double maxw = (double)__uint_as_float(mxk);

  double ss = 0.0;
#pragma unroll
  for (int i = 0; i < 32; ++i) {
    int idx = t + i * 256;
    bool sel = (kr[i] > thr) || (kr[i] == thr && idx <= cut);
    if (sel) ss += exp((double)__uint_as_float(kr[i]) - maxw);
  }
  for (int o = 32; o; o >>= 1) ss += __shfl_down(ss, o);
  __syncthreads();
  if ((t & 63) == 0) redd[t >> 6] = ss;
  __syncthreads();
  const double ssum = redd[0] + redd[1] + redd[2] + redd[3];

  if (t == 0) *s_cnt = 0;
#pragma unroll
  for (int i = 0; i < 32; ++i) slot[(size_t)(t + i * 256) * N_E + e] = -1;
  __syncthreads();
  for (int i = 0; i < 32; ++i) {
    int idx = t + i * 256;
    bool sel = (kr[i] > thr) || (kr[i] == thr && idx <= cut);
    if (sel) {
      int pos = atomicAdd(s_cnt, 1);
      ib[e * SEL + pos] = idx;
      nws[e * SEL + pos] = (float)(exp((double)__uint_as_float(kr[i]) - maxw) / ssum);
      slot[(size_t)idx * N_E + e] = pos;
    }
  }
}

// ---------------- expert GEMM: 256x256x64; A via LDS (swizzled), B via global
// regs (dbuf). Cuts LDS traffic from ~256 KB/tile/CU to ~160 KB (was LDS-bound
// 1.6x vs MFMA). Same MFMA sequence/order -> eo bit-identical.
__global__ __launch_bounds__(512, 2) void k_expert_gemm(const unsigned short* __restrict__ xb,
                                                        const unsigned short* __restrict__ web,
                                                        const float* __restrict__ be,
                                                        const int* __restrict__ ib,
                                                        const float* __restrict__ nws,
                                                        unsigned short* __restrict__ eo) {
  // LDS: [buf(2)][ A 256x64 ] bf16 = 2*16384 elems = 64 KB (+rowidx/nws)
  __shared__ unsigned short S[2 * 16384];
  __shared__ int rowidx[256];
  __shared__ float nwss[256];
  const int e = blockIdx.z;
  const int bm = blockIdx.x * 256;
  const int bn = blockIdx.y * 256;
  const int t = threadIdx.x;
  const int wave = t >> 6, lane = t & 63;
  if (t < 256) {
    rowidx[t] = ib[e * SEL + bm + t];
    nwss[t] = nws[e * SEL + bm + t];
  }
  __syncthreads();
  const unsigned short* wbase = web + (size_t)e * D_IN * D_OUT;

  // A staging: 4 x 16B per thread per K-tile. LDS dest LINEAR; global source
  // col inverse-swizzled (so swizzled ds_read sees the right data).
  const unsigned short* asrc[4];
  int adst[4];
#pragma unroll
  for (int j = 0; j < 4; ++j) {
    int idx = t + j * 512;              // 0..2047
    int r = idx >> 3;                   // tile row 0..255
    int c16 = (idx & 7) ^ (r & 7);      // inverse-swizzled 16B chunk 0..7
    asrc[j] = xb + (size_t)rowidx[r] * D_IN + c16 * 8;
    adst[j] = idx * 8;                  // element offset, linear
  }

  floatx4 acc[8][4] = {};
  const int wr = wave >> 2, wc = wave & 3;   // 2x4 waves: 128x64 out each
  const int fr = lane & 15, fq = lane >> 4;
  const int swz = (fr & 7) << 3;             // element-XOR for swizzled A reads

  // B fragment base pointers: q = nt*2+kk -> row bn + wc*64 + nt*16 + fr,
  // col kk*32 + fq*8 (+ kt*64 per tile)
  const unsigned short* bptr[8];
#pragma unroll
  for (int nt = 0; nt < 4; ++nt)
#pragma unroll
    for (int kk = 0; kk < 2; ++kk)
      bptr[nt * 2 + kk] = wbase + (size_t)(bn + wc * 64 + nt * 16 + fr) * D_IN + kk * 32 + fq * 8;

#define STAGE_A(kt, buf)                                                      \
  {                                                                           \
    _Pragma("unroll")                                                         \
    for (int j = 0; j < 4; ++j)                                               \
      async_cp16(asrc[j] + (kt) * 64, S + (buf) * 16384 + adst[j]);           \
  }

#define LOADB(kt, dst)                                                        \
  {                                                                           \
    _Pragma("unroll")                                                         \
    for (int q = 0; q < 8; ++q)                                               \
      dst[q] = *(const bf16x8*)(bptr[q] + (kt) * 64);                         \
  }

  bf16x8 bfA[8], bfB[8];

  // prologue: queue order A0(4), B0(8), A1(4) -> vmcnt(4) at kt=0 waits A0+B0
  STAGE_A(0, 0);
  LOADB(0, bfA);
  STAGE_A(1, 1);

#define GEMM_STEP(kt, BCUR, BNXT)                                             \
  {                                                                           \
    if ((kt) == 15) {                                                         \
      asm volatile("s_waitcnt vmcnt(0)" ::: "memory");                        \
    } else {                                                                  \
      asm volatile("s_waitcnt vmcnt(4)" ::: "memory");                        \
    }                                                                         \
    __builtin_amdgcn_s_barrier();                                             \
    if ((kt) < 15) LOADB((kt) + 1, BNXT);                                     \
    const unsigned short* Ab = S + ((kt) & 1) * 16384;                        \
    __builtin_amdgcn_s_setprio(1);                                            \
    _Pragma("unroll")                                                         \
    for (int kk = 0; kk < 2; ++kk) {                                          \
      bf16x8 af[8];                                                           \
      _Pragma("unroll")                                                       \
      for (int mt = 0; mt < 8; ++mt)                                          \
        af[mt] = *(const bf16x8*)(Ab + (wr * 128 + mt * 16 + fr) * 64 +       \
                                  ((kk * 32 + fq * 8) ^ swz));                \
      _Pragma("unroll")                                                       \
      for (int mt = 0; mt < 8; ++mt)                                          \
        _Pragma("unroll")                                                     \
        for (int nt = 0; nt < 4; ++nt)                                        \
          acc[mt][nt] = __builtin_amdgcn_mfma_f32_16x16x32_bf16(              \
              af[mt], BCUR[nt * 2 + kk], acc[mt][nt], 0, 0, 0);               \
    }                                                                         \
    __builtin_amdgcn_s_setprio(0);                                            \
    __builtin_amdgcn_sched_barrier(0);                                        \
    __builtin_amdgcn_s_barrier();                                             \
    if ((kt) < 14) STAGE_A((kt) + 2, (kt) & 1);                               \
  }

#pragma unroll
  for (int kt2 = 0; kt2 < 16; kt2 += 2) {
    GEMM_STEP(kt2, bfA, bfB);
    GEMM_STEP(kt2 + 1, bfB, bfA);
  }
#undef GEMM_STEP
#undef STAGE_A
#undef LOADB

  float bev[4];
#pragma unroll
  for (int nt = 0; nt < 4; ++nt) bev[nt] = be[e * D_OUT + bn + wc * 64 + nt * 16 + fr];
#pragma unroll
  for (int mt = 0; mt < 8; ++mt) {
#pragma unroll
    for (int r = 0; r < 4; ++r) {
      int lrow = wr * 128 + mt * 16 + fq * 4 + r;
      float nw = nwss[lrow];
      size_t rbase = ((size_t)e * SEL + bm + lrow) * D_OUT;
#pragma unroll
      for (int nt = 0; nt < 4; ++nt) {
        int cc = bn + wc * 64 + nt * 16 + fr;
        eo[rbase + cc] = f2bf((acc[mt][nt][r] + bev[nt]) * nw);
      }
    }
  }
}

// ---------------- combine: out[b, e*D+d] = temp_sum[b,d] + sel(b,e)*eo ----------------
__global__ __launch_bounds__(256) void k_combine(const unsigned short* __restrict__ eo,
                                                 const int* __restrict__ slot,
                                                 float* __restrict__ out) {
  const int b = blockIdx.x;
  const int t = threadIdx.x;
  __shared__ int ss[8];
  if (t < 8) ss[t] = slot[(size_t)b * N_E + t];
  __syncthreads();
  const int d0 = t * 4;
  float vx[8], vy[8], vz[8], vw[8];
  float tx = 0.f, ty = 0.f, tz = 0.f, tw = 0.f;
#pragma unroll
  for (int e = 0; e < 8; ++e) {
    int k = ss[e];
    if (k >= 0) {
      ushort4 u = *(const ushort4*)(eo + ((size_t)e * SEL + k) * D_OUT + d0);
      vx[e] = bf2f(u.x); vy[e] = bf2f(u.y); vz[e] = bf2f(u.z); vw[e] = bf2f(u.w);
      tx += vx[e]; ty += vy[e]; tz += vz[e]; tw += vw[e];
    } else {
      vx[e] = 0.f; vy[e] = 0.f; vz[e] = 0.f; vw[e] = 0.f;
    }
  }
#pragma unroll
  for (int e = 0; e < 8; ++e) {
    float4 o;
    o.x = tx + vx[e]; o.y = ty + vy[e]; o.z = tz + vz[e]; o.w = tw + vw[e];
    *(float4*)(out + (size_t)b * (N_E * D_OUT) + e * D_OUT + d0) = o;
  }
}

extern "C" void kernel_launch(void* const* d_in, const int* in_sizes, int n_in,
                              void* d_out, int out_size, void* d_ws, size_t ws_size,
                              hipStream_t stream) {
  const float* x  = (const float*)d_in[0];
  const float* w1 = (const float*)d_in[1];
  const float* b1 = (const float*)d_in[2];
  const float* wg = (const float*)d_in[3];
  const float* bg = (const float*)d_in[4];
  const float* w2 = (const float*)d_in[5];
  const float* b2 = (const float*)d_in[6];
  const float* we = (const float*)d_in[7];
  const float* be = (const float*)d_in[8];
  float* out = (float*)d_out;

  char* ws = (char*)d_ws;
  size_t off = 0;
  auto alloc = [&](size_t bytes) -> void* {
    void* p = ws + off;
    off += (bytes + 255) & ~(size_t)255;
    return p;
  };
  unsigned short* xb  = (unsigned short*)alloc((size_t)B_TOK * D_IN * 2);
  unsigned short* web = (unsigned short*)alloc((size_t)N_E * D_IN * D_OUT * 2);
  unsigned short* eo  = (unsigned short*)alloc((size_t)N_E * SEL * D_OUT * 2);
  double* lgts  = (double*)alloc((size_t)B_TOK * N_E * 8);
  int* ibuf     = (int*)alloc((size_t)N_E * SEL * 4);
  float* nws    = (float*)alloc((size_t)N_E * SEL * 4);
  int* slot     = (int*)alloc((size_t)B_TOK * N_E * 4);
  if (off > ws_size) return;  // insufficient workspace; fail loudly via wrong output

  hipLaunchKernelGGL(k_router, dim3(B_TOK / 32), dim3(256), 0, stream,
                     x, w1, b1, wg, bg, w2, b2, xb, lgts);
  hipLaunchKernelGGL(k_topk_fat, dim3(8 + 2048), dim3(256), 0, stream,
                     lgts, we, ibuf, nws, slot, web);
  hipLaunchKernelGGL(k_expert_gemm, dim3(SEL / 256, D_OUT / 256, N_E), dim3(512), 0, stream,
                     xb, web, be, ibuf, nws, eo);
  hipLaunchKernelGGL(k_combine, dim3(B_TOK), dim3(256), 0, stream, eo, slot, out);
}

// Round 10
// 495.086 us; speedup vs baseline: 1.1348x; 1.1348x over previous
//
#include <hip/hip_runtime.h>
#include <math.h>

#define B_TOK 8192
#define D_IN 1024
#define D_OUT 1024
#define N_E 8
#define N_H 128
#define SEL 2048

using bf16x8 = __attribute__((ext_vector_type(8))) short;
using floatx4 = __attribute__((ext_vector_type(4))) float;

__device__ __forceinline__ unsigned short f2bf(float f) {
  unsigned u = __float_as_uint(f);
  u = (u + 0x7FFFu + ((u >> 16) & 1u)) >> 16;
  return (unsigned short)u;
}

__device__ __forceinline__ float bf2f(unsigned short h) {
  return __uint_as_float(((unsigned)h) << 16);
}

__device__ __forceinline__ void async_cp16(const void* g, void* l) {
  __builtin_amdgcn_global_load_lds((__attribute__((address_space(1))) void*)g,
                                   (__attribute__((address_space(3))) void*)l,
                                   16, 0, 0);
}

// ---------------- fat kernel: router (blocks 0..255) + weT cast (256..2303) ----
// Router: 32 tokens/block, 4 tok x 4 col per thread, simple __syncthreads
// staging, 37.4 KB LDS -> 4 blocks/CU both paths. h in-reg -> fp64 logits;
// xb = bf16(x) emitted; w2 read from L2 in epilogue. Best measured (R6).
__global__ __launch_bounds__(256) void k_router_fat(const float* __restrict__ x,
                                                    const float* __restrict__ w1,
                                                    const float* __restrict__ b1,
                                                    const float* __restrict__ wg,
                                                    const float* __restrict__ bg,
                                                    const float* __restrict__ w2,
                                                    const float* __restrict__ b2,
                                                    const float* __restrict__ we,
                                                    unsigned short* __restrict__ xb,
                                                    double* __restrict__ logits,
                                                    unsigned short* __restrict__ web) {
  __shared__ __align__(16) char smem[37376];
  const int t = threadIdx.x;

  if (blockIdx.x >= 256) {
    // ---- weT transpose+cast path ----
    const int wb = blockIdx.x - 256;          // 0..2047
    const int e = wb >> 8;                    // 8 experts x 256 tiles
    const int rem = wb & 255;
    const int o0 = (rem >> 4) * 64;
    const int d0 = (rem & 15) * 64;
    float (*tile)[68] = (float(*)[68])smem;
    const float* wsrc = we + (size_t)e * D_IN * D_OUT;
    unsigned short* wdst = web + (size_t)e * D_OUT * D_IN;
    const int r = t >> 4;          // 0..15
    const int c = (t & 15) * 4;    // 0..60
#pragma unroll
    for (int p = 0; p < 4; ++p) {
      float4 v = *(const float4*)(wsrc + (size_t)(d0 + r + 16 * p) * D_OUT + o0 + c);
      tile[r + 16 * p][c] = v.x; tile[r + 16 * p][c + 1] = v.y;
      tile[r + 16 * p][c + 2] = v.z; tile[r + 16 * p][c + 3] = v.w;
    }
    __syncthreads();
#pragma unroll
    for (int p = 0; p < 4; ++p) {
      int orow = r + 16 * p;
      ushort4 v;
      v.x = f2bf(tile[c + 0][orow]); v.y = f2bf(tile[c + 1][orow]);
      v.z = f2bf(tile[c + 2][orow]); v.w = f2bf(tile[c + 3][orow]);
      *(ushort4*)(wdst + (size_t)(o0 + orow) * D_IN + d0 + c) = v;
    }
    return;
  }

  // ---- router path ----
  float (*xs)[36]   = (float(*)[36])(smem);              // 32x36x4  = 4608
  float (*ws1)[128] = (float(*)[128])(smem + 4608);      // 32x128x4 = 16384
  float (*wsg)[128] = (float(*)[128])(smem + 4608 + 16384);  // 16384
  const int b0 = blockIdx.x * 32;
  const int tg = t >> 5;   // 0..7 -> 4 tokens each
  const int og = t & 31;   // 0..31 -> 4 h-cols each
  const int xr = t >> 3, xc = (t & 7) * 4;   // xs loader coords

  double d1[4][4] = {}; double dg[4][4] = {};
  for (int k0 = 0; k0 < D_IN; k0 += 32) {
    __syncthreads();
    {
      float4 v = *(const float4*)(x + (size_t)(b0 + xr) * D_IN + k0 + xc);
      *(float4*)(&xs[xr][xc]) = v;
      ushort4 u; u.x = f2bf(v.x); u.y = f2bf(v.y); u.z = f2bf(v.z); u.w = f2bf(v.w);
      *(ushort4*)(xb + (size_t)(b0 + xr) * D_IN + k0 + xc) = u;
    }
    {
      int r = t >> 5, c = (t & 31) * 4;
#pragma unroll
      for (int p = 0; p < 4; ++p) {
        *(float4*)(&ws1[r + 8 * p][c]) = *(const float4*)(w1 + (size_t)(k0 + r + 8 * p) * N_H + c);
        *(float4*)(&wsg[r + 8 * p][c]) = *(const float4*)(wg + (size_t)(k0 + r + 8 * p) * N_H + c);
      }
    }
    __syncthreads();
    float a1[4][4] = {}; float ag[4][4] = {};
    for (int k = 0; k < 32; k += 4) {
      float xk[4][4];
#pragma unroll
      for (int i = 0; i < 4; ++i) {
        float4 xv = *(const float4*)(&xs[tg * 4 + i][k]);
        xk[i][0] = xv.x; xk[i][1] = xv.y; xk[i][2] = xv.z; xk[i][3] = xv.w;
      }
#pragma unroll
      for (int kk = 0; kk < 4; ++kk) {
        float4 w1v = *(const float4*)(&ws1[k + kk][og * 4]);
        float4 wgv = *(const float4*)(&wsg[k + kk][og * 4]);
        float wa1[4] = {w1v.x, w1v.y, w1v.z, w1v.w};
        float wag[4] = {wgv.x, wgv.y, wgv.z, wgv.w};
#pragma unroll
        for (int i = 0; i < 4; ++i) {
#pragma unroll
          for (int j = 0; j < 4; ++j) {
            a1[i][j] += xk[i][kk] * wa1[j];
            ag[i][j] += xk[i][kk] * wag[j];
          }
        }
      }
    }
#pragma unroll
    for (int i = 0; i < 4; ++i)
#pragma unroll
      for (int j = 0; j < 4; ++j) { d1[i][j] += a1[i][j]; dg[i][j] += ag[i][j]; }
  }

  float4 b1v = *(const float4*)(b1 + og * 4);
  float4 bgv = *(const float4*)(bg + og * 4);
  float b1a[4] = {b1v.x, b1v.y, b1v.z, b1v.w};
  float bga[4] = {bgv.x, bgv.y, bgv.z, bgv.w};
  float hv[4][4];
#pragma unroll
  for (int i = 0; i < 4; ++i) {
#pragma unroll
    for (int j = 0; j < 4; ++j) {
      float a = (float)d1[i][j] + b1a[j];
      float g = (float)dg[i][j] + bga[j];
      g = fmaxf(g, 0.f);
      hv[i][j] = fmaxf(a * g, 0.f);
    }
  }

  // logits partials (double); w2 read straight from L2 (4 KB, broadcast)
  double lp[4][8] = {};
#pragma unroll
  for (int j = 0; j < 4; ++j) {
    int kk = og * 4 + j;
    float4 wlo = *(const float4*)(w2 + kk * N_E);
    float4 whi = *(const float4*)(w2 + kk * N_E + 4);
    float w2a[8] = {wlo.x, wlo.y, wlo.z, wlo.w, whi.x, whi.y, whi.z, whi.w};
#pragma unroll
    for (int i = 0; i < 4; ++i) {
      double hj = (double)hv[i][j];
#pragma unroll
      for (int e = 0; e < 8; ++e)
        lp[i][e] += hj * (double)w2a[e];
    }
  }
#pragma unroll
  for (int o = 16; o; o >>= 1) {
#pragma unroll
    for (int i = 0; i < 4; ++i)
#pragma unroll
      for (int e = 0; e < 8; ++e)
        lp[i][e] += __shfl_down(lp[i][e], o);
  }
  if (og == 0) {
#pragma unroll
    for (int i = 0; i < 4; ++i)
#pragma unroll
      for (int e = 0; e < 8; ++e)
        logits[(size_t)(b0 + tg * 4 + i) * N_E + e] = lp[i][e] + (double)b2[e];
  }
}

// ---------------- softmax(axis=0) + exact top-2048 per expert ----------------
__global__ __launch_bounds__(256) void k_topk(const double* __restrict__ logits,
                                              int* __restrict__ ib, float* __restrict__ nws,
                                              int* __restrict__ slot) {
  const int e = blockIdx.x;
  const int t = threadIdx.x;
  __shared__ double redd[4];
  __shared__ int redi[4];
  __shared__ unsigned redu[4];
  __shared__ int s_cnt;

  double lv[32];
#pragma unroll
  for (int i = 0; i < 32; ++i) lv[i] = logits[(size_t)(t + i * 256) * N_E + e];

  double m = -1e300;
#pragma unroll
  for (int i = 0; i < 32; ++i) m = fmax(m, lv[i]);
  for (int o = 32; o; o >>= 1) m = fmax(m, __shfl_down(m, o));
  __syncthreads();
  if ((t & 63) == 0) redd[t >> 6] = m;
  __syncthreads();
  const double maxl = fmax(fmax(redd[0], redd[1]), fmax(redd[2], redd[3]));

  // cache exp(lv - maxl): reused for sum and keys (identical bits, half the exps)
  double ev[32];
#pragma unroll
  for (int i = 0; i < 32; ++i) ev[i] = exp(lv[i] - maxl);

  double s = 0.0;
#pragma unroll
  for (int i = 0; i < 32; ++i) s += ev[i];
  for (int o = 32; o; o >>= 1) s += __shfl_down(s, o);
  __syncthreads();
  if ((t & 63) == 0) redd[t >> 6] = s;
  __syncthreads();
  const double sum = redd[0] + redd[1] + redd[2] + redd[3];

  unsigned kr[32];
#pragma unroll
  for (int i = 0; i < 32; ++i) {
    float lf = (float)(ev[i] / sum);
    kr[i] = __float_as_uint(lf);
  }

  // ---- common-prefix skip: block min/max of keys ----
  unsigned mnk = 0xFFFFFFFFu, mxk = 0;
#pragma unroll
  for (int i = 0; i < 32; ++i) { mnk = (kr[i] < mnk) ? kr[i] : mnk; mxk = (kr[i] > mxk) ? kr[i] : mxk; }
  for (int o = 32; o; o >>= 1) {
    unsigned v = __shfl_down(mnk, o); mnk = (v < mnk) ? v : mnk;
    unsigned w = __shfl_down(mxk, o); mxk = (w > mxk) ? w : mxk;
  }
  __syncthreads();
  if ((t & 63) == 0) redu[t >> 6] = mnk;
  __syncthreads();
  mnk = redu[0]; if (redu[1] < mnk) mnk = redu[1]; if (redu[2] < mnk) mnk = redu[2]; if (redu[3] < mnk) mnk = redu[3];
  __syncthreads();
  if ((t & 63) == 0) redu[t >> 6] = mxk;
  __syncthreads();
  mxk = redu[0]; if (redu[1] > mxk) mxk = redu[1]; if (redu[2] > mxk) mxk = redu[2]; if (redu[3] > mxk) mxk = redu[3];

  const unsigned diff = mnk ^ mxk;
  int hb = -1;
  unsigned thr;
  if (diff == 0) {
    thr = mnk;
  } else {
    hb = 31 - __clz(diff);
    thr = mxk & ~((hb >= 31) ? 0xFFFFFFFFu : ((1u << (hb + 1)) - 1u));
  }

  for (int bit = hb; bit >= 0; --bit) {
    unsigned trial = thr | (1u << bit);
    int c = 0;
#pragma unroll
    for (int i = 0; i < 32; ++i) c += (kr[i] >= trial) ? 1 : 0;
    for (int o = 32; o; o >>= 1) c += __shfl_down(c, o);
    __syncthreads();
    if ((t & 63) == 0) redi[t >> 6] = c;
    __syncthreads();
    c = redi[0] + redi[1] + redi[2] + redi[3];
    if (c >= SEL) thr = trial;
  }

  int c1 = 0, ceq = 0;
#pragma unroll
  for (int i = 0; i < 32; ++i) {
    c1 += (kr[i] > thr) ? 1 : 0;
    ceq += (kr[i] == thr) ? 1 : 0;
  }
  for (int o = 32; o; o >>= 1) { c1 += __shfl_down(c1, o); ceq += __shfl_down(ceq, o); }
  __syncthreads();
  if ((t & 63) == 0) { redi[t >> 6] = c1; ((int*)redu)[t >> 6] = ceq; }
  __syncthreads();
  c1 = redi[0] + redi[1] + redi[2] + redi[3];
  ceq = ((int*)redu)[0] + ((int*)redu)[1] + ((int*)redu)[2] + ((int*)redu)[3];
  const int need = SEL - c1;

  int cut;
  if (ceq == need) {
    cut = B_TOK;
  } else {
    cut = 0;
    for (int bit = 12; bit >= 0; --bit) {
      int trial = cut | (1 << bit);
      int c = 0;
#pragma unroll
      for (int i = 0; i < 32; ++i) c += (kr[i] == thr && (t + i * 256) < trial) ? 1 : 0;
      for (int o = 32; o; o >>= 1) c += __shfl_down(c, o);
      __syncthreads();
      if ((t & 63) == 0) redi[t >> 6] = c;
      __syncthreads();
      c = redi[0] + redi[1] + redi[2] + redi[3];
      if (c < need) cut = trial;
    }
  }

  const double maxw = (double)__uint_as_float(mxk);

  double ss = 0.0;
#pragma unroll
  for (int i = 0; i < 32; ++i) {
    int idx = t + i * 256;
    bool sel = (kr[i] > thr) || (kr[i] == thr && idx <= cut);
    if (sel) ss += exp((double)__uint_as_float(kr[i]) - maxw);
  }
  for (int o = 32; o; o >>= 1) ss += __shfl_down(ss, o);
  __syncthreads();
  if ((t & 63) == 0) redd[t >> 6] = ss;
  __syncthreads();
  const double ssum = redd[0] + redd[1] + redd[2] + redd[3];

  if (t == 0) s_cnt = 0;
#pragma unroll
  for (int i = 0; i < 32; ++i) slot[(size_t)(t + i * 256) * N_E + e] = -1;
  __syncthreads();
  for (int i = 0; i < 32; ++i) {
    int idx = t + i * 256;
    bool sel = (kr[i] > thr) || (kr[i] == thr && idx <= cut);
    if (sel) {
      int pos = atomicAdd(&s_cnt, 1);
      ib[e * SEL + pos] = idx;
      nws[e * SEL + pos] = (float)(exp((double)__uint_as_float(kr[i]) - maxw) / ssum);
      slot[(size_t)idx * N_E + e] = pos;
    }
  }
}

// ---------------- expert GEMM: 256x256x64, dbuf LDS, counted vmcnt, swizzled ----
// eo[e][k][o] = (x[ib]@we[e] + be)*nws  (bf16 out)
__global__ __launch_bounds__(512, 2) void k_expert_gemm(const unsigned short* __restrict__ xb,
                                                        const unsigned short* __restrict__ web,
                                                        const float* __restrict__ be,
                                                        const int* __restrict__ ib,
                                                        const float* __restrict__ nws,
                                                        unsigned short* __restrict__ eo) {
  // LDS: [buf(2)][ A 256x64 | B 256x64 ] bf16 = 2*32768 elems = 128 KB (+rowidx/nws)
  __shared__ unsigned short S[2 * 32768];
  __shared__ int rowidx[256];
  __shared__ float nwss[256];
  const int e = blockIdx.z;
  const int bm = blockIdx.x * 256;
  const int bn = blockIdx.y * 256;
  const int t = threadIdx.x;
  const int wave = t >> 6, lane = t & 63;
  if (t < 256) {
    rowidx[t] = ib[e * SEL + bm + t];
    nwss[t] = nws[e * SEL + bm + t];
  }
  __syncthreads();
  const unsigned short* wbase = web + (size_t)e * D_IN * D_OUT;

  const unsigned short* asrc[4];
  const unsigned short* bsrc[4];
  int adst[4], bdst[4];
#pragma unroll
  for (int j = 0; j < 4; ++j) {
    int idx = t + j * 512;              // 0..2047
    int r = idx >> 3;                   // tile row 0..255
    int c16 = (idx & 7) ^ (r & 7);      // inverse-swizzled 16B chunk 0..7
    asrc[j] = xb + (size_t)rowidx[r] * D_IN + c16 * 8;
    adst[j] = idx * 8;                  // element offset, linear
    bsrc[j] = wbase + (size_t)(bn + r) * D_IN + c16 * 8;
    bdst[j] = 16384 + idx * 8;
  }

#define STAGE(kt, buf)                                                        \
  {                                                                           \
    _Pragma("unroll")                                                         \
    for (int j = 0; j < 4; ++j) {                                             \
      async_cp16(asrc[j] + (kt) * 64, S + (buf) * 32768 + adst[j]);           \
      async_cp16(bsrc[j] + (kt) * 64, S + (buf) * 32768 + bdst[j]);           \
    }                                                                         \
  }

  floatx4 acc[8][4] = {};
  const int wr = wave >> 2, wc = wave & 3;   // 2x4 waves: 128x64 out each
  const int fr = lane & 15, fq = lane >> 4;
  const int swz = (fr & 7) << 3;             // element-XOR for swizzled reads

  STAGE(0, 0);
  STAGE(1, 1);

  for (int kt = 0; kt < 16; ++kt) {
    const int cur = kt & 1;
    if (kt == 15) {
      asm volatile("s_waitcnt vmcnt(0)" ::: "memory");
    } else {
      asm volatile("s_waitcnt vmcnt(8)" ::: "memory");
    }
    __builtin_amdgcn_s_barrier();
    const unsigned short* Ab = S + cur * 32768;
    const unsigned short* Bb = Ab + 16384;
    __builtin_amdgcn_s_setprio(1);
#pragma unroll
    for (int kk = 0; kk < 2; ++kk) {
      bf16x8 af[8], bfr[4];
#pragma unroll
      for (int mt = 0; mt < 8; ++mt)
        af[mt] = *(const bf16x8*)(Ab + (wr * 128 + mt * 16 + fr) * 64 + ((kk * 32 + fq * 8) ^ swz));
#pragma unroll
      for (int nt = 0; nt < 4; ++nt)
        bfr[nt] = *(const bf16x8*)(Bb + (wc * 64 + nt * 16 + fr) * 64 + ((kk * 32 + fq * 8) ^ swz));
#pragma unroll
      for (int mt = 0; mt < 8; ++mt)
#pragma unroll
        for (int nt = 0; nt < 4; ++nt)
          acc[mt][nt] = __builtin_amdgcn_mfma_f32_16x16x32_bf16(af[mt], bfr[nt], acc[mt][nt], 0, 0, 0);
    }
    __builtin_amdgcn_s_setprio(0);
    __builtin_amdgcn_sched_barrier(0);
    __builtin_amdgcn_s_barrier();
    if (kt < 14) STAGE(kt + 2, cur);
  }
#undef STAGE

  float bev[4];
#pragma unroll
  for (int nt = 0; nt < 4; ++nt) bev[nt] = be[e * D_OUT + bn + wc * 64 + nt * 16 + fr];
#pragma unroll
  for (int mt = 0; mt < 8; ++mt) {
#pragma unroll
    for (int r = 0; r < 4; ++r) {
      int lrow = wr * 128 + mt * 16 + fq * 4 + r;
      float nw = nwss[lrow];
      size_t rbase = ((size_t)e * SEL + bm + lrow) * D_OUT;
#pragma unroll
      for (int nt = 0; nt < 4; ++nt) {
        int cc = bn + wc * 64 + nt * 16 + fr;
        eo[rbase + cc] = f2bf((acc[mt][nt][r] + bev[nt]) * nw);
      }
    }
  }
}

// ---------------- combine: out[b, e*D+d] = temp_sum[b,d] + sel(b,e)*eo ----------------
__global__ __launch_bounds__(256) void k_combine(const unsigned short* __restrict__ eo,
                                                 const int* __restrict__ slot,
                                                 float* __restrict__ out) {
  const int b = blockIdx.x;
  const int t = threadIdx.x;
  __shared__ int ss[8];
  if (t < 8) ss[t] = slot[(size_t)b * N_E + t];
  __syncthreads();
  const int d0 = t * 4;
  float vx[8], vy[8], vz[8], vw[8];
  float tx = 0.f, ty = 0.f, tz = 0.f, tw = 0.f;
#pragma unroll
  for (int e = 0; e < 8; ++e) {
    int k = ss[e];
    if (k >= 0) {
      ushort4 u = *(const ushort4*)(eo + ((size_t)e * SEL + k) * D_OUT + d0);
      vx[e] = bf2f(u.x); vy[e] = bf2f(u.y); vz[e] = bf2f(u.z); vw[e] = bf2f(u.w);
      tx += vx[e]; ty += vy[e]; tz += vz[e]; tw += vw[e];
    } else {
      vx[e] = 0.f; vy[e] = 0.f; vz[e] = 0.f; vw[e] = 0.f;
    }
  }
#pragma unroll
  for (int e = 0; e < 8; ++e) {
    float4 o;
    o.x = tx + vx[e]; o.y = ty + vy[e]; o.z = tz + vz[e]; o.w = tw + vw[e];
    *(float4*)(out + (size_t)b * (N_E * D_OUT) + e * D_OUT + d0) = o;
  }
}

extern "C" void kernel_launch(void* const* d_in, const int* in_sizes, int n_in,
                              void* d_out, int out_size, void* d_ws, size_t ws_size,
                              hipStream_t stream) {
  const float* x  = (const float*)d_in[0];
  const float* w1 = (const float*)d_in[1];
  const float* b1 = (const float*)d_in[2];
  const float* wg = (const float*)d_in[3];
  const float* bg = (const float*)d_in[4];
  const float* w2 = (const float*)d_in[5];
  const float* b2 = (const float*)d_in[6];
  const float* we = (const float*)d_in[7];
  const float* be = (const float*)d_in[8];
  float* out = (float*)d_out;

  char* ws = (char*)d_ws;
  size_t off = 0;
  auto alloc = [&](size_t bytes) -> void* {
    void* p = ws + off;
    off += (bytes + 255) & ~(size_t)255;
    return p;
  };
  unsigned short* xb  = (unsigned short*)alloc((size_t)B_TOK * D_IN * 2);
  unsigned short* web = (unsigned short*)alloc((size_t)N_E * D_IN * D_OUT * 2);
  unsigned short* eo  = (unsigned short*)alloc((size_t)N_E * SEL * D_OUT * 2);
  double* lgts  = (double*)alloc((size_t)B_TOK * N_E * 8);
  int* ibuf     = (int*)alloc((size_t)N_E * SEL * 4);
  float* nws    = (float*)alloc((size_t)N_E * SEL * 4);
  int* slot     = (int*)alloc((size_t)B_TOK * N_E * 4);
  if (off > ws_size) return;  // insufficient workspace; fail loudly via wrong output

  hipLaunchKernelGGL(k_router_fat, dim3(256 + 2048), dim3(256), 0, stream,
                     x, w1, b1, wg, bg, w2, b2, we, xb, lgts, web);
  hipLaunchKernelGGL(k_topk, dim3(N_E), dim3(256), 0, stream, lgts, ibuf, nws, slot);
  hipLaunchKernelGGL(k_expert_gemm, dim3(SEL / 256, D_OUT / 256, N_E), dim3(512), 0, stream,
                     xb, web, be, ibuf, nws, eo);
  hipLaunchKernelGGL(k_combine, dim3(B_TOK), dim3(256), 0, stream, eo, slot, out);
}